// Round 1
// baseline (286.651 us; speedup 1.0000x reference)
//
#include <hip/hip_runtime.h>
#include <hip/hip_bf16.h>
#include <cstdint>
#include <cstddef>

#define Bb 4
#define Tt 2048
#define Ee 512
#define Hh 8
#define Dd 64
#define HD 512
#define BT 8192

typedef __bf16 bf16x8 __attribute__((ext_vector_type(8)));
typedef __bf16 bf16x4 __attribute__((ext_vector_type(4)));
typedef float f32x4 __attribute__((ext_vector_type(4)));

__device__ __forceinline__ f32x4 mfma16(bf16x8 a, bf16x8 b, f32x4 c) {
  return __builtin_amdgcn_mfma_f32_16x16x32_bf16(a, b, c, 0, 0, 0);
}

// ---- weight conversion: 4 x [512x512] f32 -> bf16 (Wq,Wk,Wv already [hd][e]; Wo is [e][hd]) ----
__global__ void cvt_w_kernel(const float* __restrict__ wq, const float* __restrict__ wk,
                             const float* __restrict__ wv, const float* __restrict__ wo,
                             __bf16* __restrict__ dst) {
  int i = (blockIdx.x * 256 + threadIdx.x) * 4;
  int a = i >> 18;
  int off = i & ((1 << 18) - 1);
  const float* src = (a == 0) ? wq : (a == 1) ? wk : (a == 2) ? wv : wo;
  float4 f = *(const float4*)(src + off);
  bf16x4 o;
  o[0] = (__bf16)f.x; o[1] = (__bf16)f.y; o[2] = (__bf16)f.z; o[3] = (__bf16)f.w;
  *(bf16x4*)(dst + i) = o;
}

// ---- QKV projection GEMM: A[8192x512] f32 (row-major) x W[512x512] bf16 ([N][K]) ----
// blockIdx.z selects 0=Q->qh[B,H,T,D], 1=K->kh[B,H,T,D], 2=V->vt[B,H,D,T]
__global__ __launch_bounds__(256)
void gemm_qkv_kernel(const float* __restrict__ Aq, const float* __restrict__ Ak,
                     const float* __restrict__ Av, const __bf16* __restrict__ Wall,
                     __bf16* __restrict__ qh, __bf16* __restrict__ kh, __bf16* __restrict__ vt) {
  const int pz = blockIdx.z;
  const float* A = (pz == 0) ? Aq : (pz == 1) ? Ak : Av;
  const __bf16* Bw = Wall + (size_t)pz * HD * Ee;
  const int row0 = blockIdx.y * 128;
  const int col0 = blockIdx.x * 128;

  __shared__ __align__(16) __bf16 As[128 * 32];
  __shared__ __align__(16) __bf16 Bs[128 * 32];
  char* As8 = (char*)As;
  char* Bs8 = (char*)Bs;

  const int tid = threadIdx.x;
  const int l = tid & 63, w = tid >> 6;
  const int ln = l & 15, lg = l >> 4;
  const int wr = (w >> 1) * 64, wc = (w & 1) * 64;

  const int sr = tid >> 1;            // staging row 0..127
  const int sce = (tid & 1) * 16;     // staging col (elems)
  const int sbyte = sr * 64 + sce * 2;
  const int swz = (sr & 7) << 4;

  f32x4 acc[4][4] = {};

  for (int kt = 0; kt < Ee; kt += 32) {
    const float* ag = A + (size_t)(row0 + sr) * Ee + kt + sce;
    float4 a0 = *(const float4*)(ag);
    float4 a1 = *(const float4*)(ag + 4);
    float4 a2 = *(const float4*)(ag + 8);
    float4 a3 = *(const float4*)(ag + 12);
    const __bf16* bg = Bw + (size_t)(col0 + sr) * Ee + kt + sce;
    bf16x8 b0 = *(const bf16x8*)(bg);
    bf16x8 b1 = *(const bf16x8*)(bg + 8);
    bf16x8 c0, c1;
    c0[0] = (__bf16)a0.x; c0[1] = (__bf16)a0.y; c0[2] = (__bf16)a0.z; c0[3] = (__bf16)a0.w;
    c0[4] = (__bf16)a1.x; c0[5] = (__bf16)a1.y; c0[6] = (__bf16)a1.z; c0[7] = (__bf16)a1.w;
    c1[0] = (__bf16)a2.x; c1[1] = (__bf16)a2.y; c1[2] = (__bf16)a2.z; c1[3] = (__bf16)a2.w;
    c1[4] = (__bf16)a3.x; c1[5] = (__bf16)a3.y; c1[6] = (__bf16)a3.z; c1[7] = (__bf16)a3.w;
    __syncthreads();
    *(bf16x8*)(As8 + ((sbyte) ^ swz)) = c0;
    *(bf16x8*)(As8 + ((sbyte + 16) ^ swz)) = c1;
    *(bf16x8*)(Bs8 + ((sbyte) ^ swz)) = b0;
    *(bf16x8*)(Bs8 + ((sbyte + 16) ^ swz)) = b1;
    __syncthreads();
    bf16x8 af[4], bfr[4];
#pragma unroll
    for (int mi = 0; mi < 4; mi++) {
      int r = wr + mi * 16 + ln;
      af[mi] = *(const bf16x8*)(As8 + ((r * 64 + lg * 16) ^ ((r & 7) << 4)));
    }
#pragma unroll
    for (int ni = 0; ni < 4; ni++) {
      int r = wc + ni * 16 + ln;
      bfr[ni] = *(const bf16x8*)(Bs8 + ((r * 64 + lg * 16) ^ ((r & 7) << 4)));
    }
#pragma unroll
    for (int mi = 0; mi < 4; mi++)
#pragma unroll
      for (int ni = 0; ni < 4; ni++)
        acc[mi][ni] = mfma16(af[mi], bfr[ni], acc[mi][ni]);
  }

#pragma unroll
  for (int mi = 0; mi < 4; mi++) {
    const int rowb = row0 + wr + mi * 16 + lg * 4;  // bt base (4 consecutive t)
    const int bb = rowb >> 11;
    const int t0 = rowb & (Tt - 1);
#pragma unroll
    for (int ni = 0; ni < 4; ni++) {
      const int colb = col0 + wc + ni * 16 + ln;    // hd
      const int hh = colb >> 6;
      const int dd = colb & 63;
      if (pz == 2) {
        bf16x4 pk;
#pragma unroll
        for (int r = 0; r < 4; r++) pk[r] = (__bf16)acc[mi][ni][r];
        *(bf16x4*)(vt + ((size_t)(bb * Hh + hh) * Dd + dd) * Tt + t0) = pk;
      } else {
        __bf16* dstp = (pz == 0 ? qh : kh) + ((size_t)(bb * Hh + hh) * Tt + t0) * Dd + dd;
#pragma unroll
        for (int r = 0; r < 4; r++) dstp[(size_t)r * Dd] = (__bf16)acc[mi][ni][r];
      }
    }
  }
}

// ---- flash attention: block=(qtile,h,b), 4 waves x 16 q-rows, KV tiles of 64 ----
__global__ __launch_bounds__(256)
void attn_kernel(const __bf16* __restrict__ qh, const __bf16* __restrict__ kh,
                 const __bf16* __restrict__ vt, __bf16* __restrict__ att) {
  const int qt = blockIdx.x;
  const int hh = blockIdx.y;
  const int bb = blockIdx.z;
  const int tid = threadIdx.x;
  const int l = tid & 63, w = tid >> 6;
  const int ln = l & 15, lg = l >> 4;

  const __bf16* Q = qh + (size_t)(bb * Hh + hh) * Tt * Dd;
  const __bf16* K = kh + (size_t)(bb * Hh + hh) * Tt * Dd;
  const __bf16* V = vt + (size_t)(bb * Hh + hh) * Dd * Tt;  // [D][T]

  const int qr = qt * 64 + w * 16;

  bf16x8 qf[2];
#pragma unroll
  for (int kk = 0; kk < 2; kk++)
    qf[kk] = *(const bf16x8*)(Q + (size_t)(qr + ln) * Dd + kk * 32 + lg * 8);

  f32x4 oacc[4] = {};
  float mrun[4], srun[4];
#pragma unroll
  for (int r = 0; r < 4; r++) { mrun[r] = -1e30f; srun[r] = 0.f; }

  __shared__ __align__(16) char plds[4][2048];  // per-wave P tile [16][64] bf16, swizzled
  char* P8 = plds[w];

  for (int st = 0; st <= qt; ++st) {
    const int s0 = st * 64;
    f32x4 sacc[4] = {};
#pragma unroll
    for (int kk = 0; kk < 2; kk++) {
#pragma unroll
      for (int ni = 0; ni < 4; ni++) {
        bf16x8 kf = *(const bf16x8*)(K + (size_t)(s0 + ni * 16 + ln) * Dd + kk * 32 + lg * 8);
        sacc[ni] = mfma16(qf[kk], kf, sacc[ni]);
      }
    }
    const bool diag = (st == qt);
#pragma unroll
    for (int ni = 0; ni < 4; ni++) {
#pragma unroll
      for (int r = 0; r < 4; r++) {
        float x = sacc[ni][r] * 0.125f;  // 1/sqrt(64)
        if (diag && (s0 + ni * 16 + ln) > (qr + lg * 4 + r)) x = -1e30f;
        sacc[ni][r] = x;
      }
    }
    float rmax[4];
#pragma unroll
    for (int r = 0; r < 4; r++)
      rmax[r] = fmaxf(fmaxf(sacc[0][r], sacc[1][r]), fmaxf(sacc[2][r], sacc[3][r]));
#pragma unroll
    for (int off = 1; off < 16; off <<= 1) {
#pragma unroll
      for (int r = 0; r < 4; r++)
        rmax[r] = fmaxf(rmax[r], __shfl_xor(rmax[r], off, 64));
    }
    float mnew[4], fac[4];
#pragma unroll
    for (int r = 0; r < 4; r++) {
      mnew[r] = fmaxf(mrun[r], rmax[r]);
      fac[r] = __expf(mrun[r] - mnew[r]);
      mrun[r] = mnew[r];
    }
    float rsum[4] = {0.f, 0.f, 0.f, 0.f};
#pragma unroll
    for (int ni = 0; ni < 4; ni++) {
#pragma unroll
      for (int r = 0; r < 4; r++) {
        float p = __expf(sacc[ni][r] - mnew[r]);
        sacc[ni][r] = p;
        rsum[r] += p;
      }
    }
#pragma unroll
    for (int off = 1; off < 16; off <<= 1) {
#pragma unroll
      for (int r = 0; r < 4; r++)
        rsum[r] += __shfl_xor(rsum[r], off, 64);
    }
#pragma unroll
    for (int r = 0; r < 4; r++)
      srun[r] = srun[r] * fac[r] + rsum[r];
#pragma unroll
    for (int nd = 0; nd < 4; nd++)
#pragma unroll
      for (int r = 0; r < 4; r++)
        oacc[nd][r] *= fac[r];
    // transpose P through per-wave LDS (swizzled rows, 2B scattered writes)
#pragma unroll
    for (int ni = 0; ni < 4; ni++) {
#pragma unroll
      for (int r = 0; r < 4; r++) {
        int prow = lg * 4 + r;
        int off = (prow * 128 + (ni * 16 + ln) * 2) ^ ((prow & 7) << 4);
        *(__bf16*)(P8 + off) = (__bf16)sacc[ni][r];
      }
    }
    asm volatile("s_waitcnt lgkmcnt(0)" ::: "memory");  // in-wave fence: P writes visible
#pragma unroll
    for (int kk = 0; kk < 2; kk++) {
      int poff = (ln * 128 + kk * 64 + lg * 16) ^ ((ln & 7) << 4);
      bf16x8 pf = *(const bf16x8*)(P8 + poff);
#pragma unroll
      for (int nd = 0; nd < 4; nd++) {
        bf16x8 vf = *(const bf16x8*)(V + (size_t)(nd * 16 + ln) * Tt + s0 + kk * 32 + lg * 8);
        oacc[nd] = mfma16(pf, vf, oacc[nd]);
      }
    }
    asm volatile("s_waitcnt lgkmcnt(0)" ::: "memory");  // P reads done before next overwrite
  }

#pragma unroll
  for (int nd = 0; nd < 4; nd++) {
#pragma unroll
    for (int r = 0; r < 4; r++) {
      float v = oacc[nd][r] / srun[r];
      int row = bb * Tt + qr + lg * 4 + r;
      int col = hh * 64 + nd * 16 + ln;
      att[(size_t)row * HD + col] = (__bf16)v;
    }
  }
}

// ---- output projection: att[8192x512] bf16 x Wo[512x512] bf16 ([N][K]) + bo -> f32 ----
__global__ __launch_bounds__(256)
void gemm_out_kernel(const __bf16* __restrict__ att, const __bf16* __restrict__ Wo,
                     const float* __restrict__ bo, float* __restrict__ out) {
  const int row0 = blockIdx.y * 128;
  const int col0 = blockIdx.x * 128;
  __shared__ __align__(16) __bf16 As[128 * 32];
  __shared__ __align__(16) __bf16 Bs[128 * 32];
  char* As8 = (char*)As;
  char* Bs8 = (char*)Bs;
  const int tid = threadIdx.x;
  const int l = tid & 63, w = tid >> 6;
  const int ln = l & 15, lg = l >> 4;
  const int wr = (w >> 1) * 64, wc = (w & 1) * 64;
  const int sr = tid >> 1;
  const int sce = (tid & 1) * 16;
  const int sbyte = sr * 64 + sce * 2;
  const int swz = (sr & 7) << 4;
  f32x4 acc[4][4] = {};

  for (int kt = 0; kt < HD; kt += 32) {
    const __bf16* ag = att + (size_t)(row0 + sr) * HD + kt + sce;
    bf16x8 a0 = *(const bf16x8*)(ag);
    bf16x8 a1 = *(const bf16x8*)(ag + 8);
    const __bf16* bg = Wo + (size_t)(col0 + sr) * HD + kt + sce;
    bf16x8 b0 = *(const bf16x8*)(bg);
    bf16x8 b1 = *(const bf16x8*)(bg + 8);
    __syncthreads();
    *(bf16x8*)(As8 + ((sbyte) ^ swz)) = a0;
    *(bf16x8*)(As8 + ((sbyte + 16) ^ swz)) = a1;
    *(bf16x8*)(Bs8 + ((sbyte) ^ swz)) = b0;
    *(bf16x8*)(Bs8 + ((sbyte + 16) ^ swz)) = b1;
    __syncthreads();
    bf16x8 af[4], bfr[4];
#pragma unroll
    for (int mi = 0; mi < 4; mi++) {
      int r = wr + mi * 16 + ln;
      af[mi] = *(const bf16x8*)(As8 + ((r * 64 + lg * 16) ^ ((r & 7) << 4)));
    }
#pragma unroll
    for (int ni = 0; ni < 4; ni++) {
      int r = wc + ni * 16 + ln;
      bfr[ni] = *(const bf16x8*)(Bs8 + ((r * 64 + lg * 16) ^ ((r & 7) << 4)));
    }
#pragma unroll
    for (int mi = 0; mi < 4; mi++)
#pragma unroll
      for (int ni = 0; ni < 4; ni++)
        acc[mi][ni] = mfma16(af[mi], bfr[ni], acc[mi][ni]);
  }

#pragma unroll
  for (int mi = 0; mi < 4; mi++) {
    const int rowb = row0 + wr + mi * 16 + lg * 4;
#pragma unroll
    for (int ni = 0; ni < 4; ni++) {
      const int col = col0 + wc + ni * 16 + ln;
      const float bias = bo[col];
#pragma unroll
      for (int r = 0; r < 4; r++)
        out[(size_t)(rowb + r) * Ee + col] = acc[mi][ni][r] + bias;
    }
  }
}

extern "C" void kernel_launch(void* const* d_in, const int* in_sizes, int n_in,
                              void* d_out, int out_size, void* d_ws, size_t ws_size,
                              hipStream_t stream) {
  (void)in_sizes; (void)n_in; (void)out_size; (void)ws_size;
  // setup_inputs order: x, k, q, v, Wq, Wk, Wv, Wo, bo
  const float* kin = (const float*)d_in[1];
  const float* qin = (const float*)d_in[2];
  const float* vin = (const float*)d_in[3];
  const float* Wq = (const float*)d_in[4];
  const float* Wk = (const float*)d_in[5];
  const float* Wv = (const float*)d_in[6];
  const float* Wo = (const float*)d_in[7];
  const float* bo = (const float*)d_in[8];
  float* out = (float*)d_out;

  // workspace layout (bf16): [Wq|Wk|Wv|Wo] (4*256K) | qh (4M) | kh (4M) | vt (4M) | att (4M)
  __bf16* wall = (__bf16*)d_ws;
  __bf16* qh = wall + (size_t)4 * 262144;
  __bf16* kh = qh + (size_t)BT * HD;
  __bf16* vt = kh + (size_t)BT * HD;
  __bf16* att = vt + (size_t)BT * HD;

  cvt_w_kernel<<<dim3(1024), dim3(256), 0, stream>>>(Wq, Wk, Wv, Wo, wall);
  gemm_qkv_kernel<<<dim3(4, 64, 3), dim3(256), 0, stream>>>(qin, kin, vin, wall, qh, kh, vt);
  attn_kernel<<<dim3(32, 8, 4), dim3(256), 0, stream>>>(qh, kh, vt, att);
  gemm_out_kernel<<<dim3(4, 64), dim3(256), 0, stream>>>(att, wall + (size_t)3 * 262144, bo, out);
}